// Round 2
// baseline (34.559 us; speedup 1.0000x reference)
//
#include <hip/hip_runtime.h>

#define B_DIM 4096
#define L_DIM 512
#define NT 1000
#define OD 8
// Padded LDS layout: row r, elem j lives at float offset 8r + 4*(r>>2) + j.
// Bank cluster = (2*(r%4) + ((r>>2)%8) + half) % 8 -> uniform for random r.
// Max offset = 8*999 + 4*249 + 7 = 8995 -> 9000 floats = 36 KB.
#define LDS_FLOATS 9000

__global__ __launch_bounds__(256) void ste_kernel(
    const float* __restrict__ timestamp,   // (B, L+1)
    const float* __restrict__ W,           // (OD, NT)
    const float* __restrict__ bias,        // (OD,)
    float* __restrict__ out_te,            // (B, L, OD)
    float* __restrict__ out_ts)            // (B, L)
{
    __shared__ float wt[LDS_FLOATS];
    for (int k = threadIdx.x; k < NT * OD; k += 256) {
        int r = k >> 3;   // time bucket
        int j = k & 7;    // out dim
        wt[8 * r + 4 * (r >> 2) + j] = W[j * NT + r] + bias[j];
    }
    __syncthreads();

    // Pair-of-lanes: thread t handles (element e = t>>1, half = t&1).
    // Stores: consecutive lanes write consecutive 16B -> fully coalesced.
    const int total_h = B_DIM * L_DIM * 2;
    const int stride  = gridDim.x * blockDim.x;
    for (int t = blockIdx.x * blockDim.x + threadIdx.x; t < total_h; t += stride) {
        const int e    = t >> 1;
        const int half = t & 1;
        const int row  = e >> 9;              // L == 512
        const int col  = e & (L_DIM - 1);
        const float ts = timestamp[row * (L_DIM + 1) + col];

        // idx = max(floor(ts / 1000.0f), 0), clamped high (jnp.take clamps).
        float q = ts / 1000.0f;
        int idx = (int)floorf(q);
        idx = idx < 0 ? 0 : (idx > NT - 1 ? NT - 1 : idx);

        const float4 v = *reinterpret_cast<const float4*>(
            &wt[8 * idx + 4 * (idx >> 2) + 4 * half]);
        *reinterpret_cast<float4*>(out_te + (size_t)e * OD + half * 4) = v;

        if (half == 0) out_ts[e] = ts;
    }
}

extern "C" void kernel_launch(void* const* d_in, const int* in_sizes, int n_in,
                              void* d_out, int out_size, void* d_ws, size_t ws_size,
                              hipStream_t stream) {
    // Inputs (setup_inputs order): input (int32, unused), timestamp (f32),
    // W (f32, 8x1000), b (f32, 8).
    const float* timestamp = (const float*)d_in[1];
    const float* W         = (const float*)d_in[2];
    const float* bias      = (const float*)d_in[3];

    float* out = (float*)d_out;
    float* out_te = out;                                    // B*L*8 floats
    float* out_ts = out + (size_t)B_DIM * L_DIM * OD;       // B*L floats

    ste_kernel<<<2048, 256, 0, stream>>>(timestamp, W, bias, out_te, out_ts);
}

// Round 4
// 24.546 us; speedup vs baseline: 1.4079x; 1.4079x over previous
//
#include <hip/hip_runtime.h>

#define B_DIM 4096
#define L_DIM 512
#define NT 1000
#define OD 8
#define TOTAL (B_DIM * L_DIM)   // 2,097,152
#define CHUNK 1024               // elements per block
#define NBLK (TOTAL / CHUNK)     // 2048

typedef float float4n __attribute__((ext_vector_type(4)));

// Table: 2000 16-byte units (u = 2*idx + half), XOR-swizzled into a 2048-unit
// space: us = u ^ ((u>>3)&7). Bank cluster (us%8) becomes uniform for random
// idx. 2048 units * 16B = 32 KB exactly.
__device__ __forceinline__ int swz(int u) { return u ^ ((u >> 3) & 7); }

__global__ __launch_bounds__(256) void ste_kernel(
    const float* __restrict__ timestamp,   // (B, L+1)
    const float* __restrict__ W,           // (OD, NT)
    const float* __restrict__ bias,        // (OD,)
    float* __restrict__ out_te,            // (B, L, OD)
    float* __restrict__ out_ts)            // (B, L)
{
    __shared__ float wt[2048 * 4];   // 32 KB swizzled table
    __shared__ int   sidx[CHUNK];    // 4 KB

    // Build table: coalesced W reads (consecutive lanes -> consecutive r).
    #pragma unroll
    for (int j = 0; j < OD; ++j) {
        const float bj = bias[j];
        for (int r = threadIdx.x; r < NT; r += 256) {
            const float val = W[j * NT + r] + bj;
            const int u = 2 * r + (j >> 2);
            wt[swz(u) * 4 + (j & 3)] = val;
        }
    }

    const int base = blockIdx.x * CHUNK;

    // Phase A: 4 independent coalesced ts loads -> idx -> LDS; ts passthrough.
    float tsv[4];
    #pragma unroll
    for (int u = 0; u < 4; ++u) {
        const int e   = base + u * 256 + threadIdx.x;
        const int row = e >> 9;             // L == 512
        const int col = e & (L_DIM - 1);
        tsv[u] = timestamp[row * (L_DIM + 1) + col];
    }
    #pragma unroll
    for (int u = 0; u < 4; ++u) {
        float q = tsv[u] / 1000.0f;
        int idx = (int)floorf(q);
        idx = idx < 0 ? 0 : (idx > NT - 1 ? NT - 1 : idx);
        sidx[u * 256 + threadIdx.x] = idx;
        __builtin_nontemporal_store(tsv[u], &out_ts[base + u * 256 + threadIdx.x]);
    }
    __syncthreads();

    // Phase B: 8 independent gather->store chains per thread.
    // g = u*256 + tid -> element g>>1, half g&1; consecutive lanes write
    // consecutive 16B -> fully coalesced dwordx4 stores.
    #pragma unroll
    for (int u = 0; u < 8; ++u) {
        const int g    = u * 256 + threadIdx.x;
        const int el   = g >> 1;
        const int half = g & 1;
        const int idx  = sidx[el];
        const float4n v = *reinterpret_cast<const float4n*>(&wt[swz(2 * idx + half) * 4]);
        __builtin_nontemporal_store(
            v, reinterpret_cast<float4n*>(out_te + (size_t)(base + el) * OD + half * 4));
    }
}

extern "C" void kernel_launch(void* const* d_in, const int* in_sizes, int n_in,
                              void* d_out, int out_size, void* d_ws, size_t ws_size,
                              hipStream_t stream) {
    // Inputs (setup_inputs order): input (int32, unused), timestamp (f32),
    // W (f32, 8x1000), b (f32, 8).
    const float* timestamp = (const float*)d_in[1];
    const float* W         = (const float*)d_in[2];
    const float* bias      = (const float*)d_in[3];

    float* out = (float*)d_out;
    float* out_te = out;                                    // B*L*8 floats
    float* out_ts = out + (size_t)B_DIM * L_DIM * OD;       // B*L floats

    ste_kernel<<<NBLK, 256, 0, stream>>>(timestamp, W, bias, out_te, out_ts);
}

// Round 5
// 24.035 us; speedup vs baseline: 1.4379x; 1.0212x over previous
//
#include <hip/hip_runtime.h>

#define B_DIM 4096
#define L_DIM 512
#define NT 1000
#define OD 8
#define TOTAL (B_DIM * L_DIM)   // 2,097,152
#define CHUNK 2048               // elements per block
#define NBLK (TOTAL / CHUNK)     // 1024 = 4 blocks/CU x 256 CUs, one batch

typedef float float4n __attribute__((ext_vector_type(4)));

// Table: 2000 16-byte units (u = 2*idx + half), XOR-swizzled into a 2048-unit
// space: us = u ^ ((u>>3)&7). Bank cluster (us%8) uniform for random idx.
// 2048 units * 16B = 32 KB exactly. Stored PRE-SWIZZLED in d_ws so the main
// kernel can DMA it linearly with global_load_lds (linear dest requirement).
__device__ __forceinline__ int swz(int u) { return u ^ ((u >> 3) & 7); }

__global__ __launch_bounds__(256) void build_table(
    const float* __restrict__ W,     // (OD, NT)
    const float* __restrict__ bias,  // (OD,)
    float* __restrict__ wt_g)        // 2048*4 floats, swizzled layout
{
    const int k = blockIdx.x * 256 + threadIdx.x;   // 0..8191
    if (k < NT * OD) {
        const int r = k >> 3;   // time bucket
        const int j = k & 7;    // out dim
        const float val = W[j * NT + r] + bias[j];
        const int u = 2 * r + (j >> 2);
        wt_g[swz(u) * 4 + (j & 3)] = val;
    }
}

__global__ __launch_bounds__(256) void ste_kernel(
    const float* __restrict__ timestamp,   // (B, L+1)
    const float* __restrict__ wt_g,        // swizzled table in d_ws
    float* __restrict__ out_te,            // (B, L, OD)
    float* __restrict__ out_ts)            // (B, L)
{
    __shared__ float wt[2048 * 4];   // 32 KB swizzled table
    __shared__ int   sidx[CHUNK];    // 8 KB

    const int tid  = threadIdx.x;
    const int base = blockIdx.x * CHUNK;

    // (1) Issue the 8 independent ts loads FIRST (idx compute waits only on
    // these; the table DMA issued after stays in flight until the barrier).
    float tsv[8];
    #pragma unroll
    for (int u = 0; u < 8; ++u) {
        const int e   = base + u * 256 + tid;
        const int row = e >> 9;             // L == 512
        const int col = e & (L_DIM - 1);
        tsv[u] = timestamp[row * (L_DIM + 1) + col];
    }

    // (2) DMA the 32 KB table straight into LDS: 8 x (256 lanes x 16 B).
    // Linear source, linear dest -> global_load_lds applies (lane x 16B).
    #pragma unroll
    for (int u = 0; u < 8; ++u) {
        const int off = (u * 256 + tid) * 4;   // float offset, 16B per lane
        __builtin_amdgcn_global_load_lds(
            (const __attribute__((address_space(1))) void*)(wt_g + off),
            (__attribute__((address_space(3))) void*)(wt + off),
            16, 0, 0);
    }

    // (3) idx -> LDS; ts passthrough (coalesced nontemporal dwords).
    #pragma unroll
    for (int u = 0; u < 8; ++u) {
        float q = tsv[u] / 1000.0f;
        int idx = (int)floorf(q);
        idx = idx < 0 ? 0 : (idx > NT - 1 ? NT - 1 : idx);
        sidx[u * 256 + tid] = idx;
        __builtin_nontemporal_store(tsv[u], &out_ts[base + u * 256 + tid]);
    }
    __syncthreads();   // drains table DMA + sidx writes

    // (4) 16 independent gather->store chains per thread. g = u*256+tid ->
    // element g>>1, half g&1; consecutive lanes write consecutive 16B.
    #pragma unroll
    for (int u = 0; u < 16; ++u) {
        const int g    = u * 256 + tid;
        const int el   = g >> 1;
        const int half = g & 1;
        const int idx  = sidx[el];
        const float4n v =
            *reinterpret_cast<const float4n*>(&wt[swz(2 * idx + half) * 4]);
        __builtin_nontemporal_store(
            v, reinterpret_cast<float4n*>(out_te + (size_t)(base + el) * OD + half * 4));
    }
}

extern "C" void kernel_launch(void* const* d_in, const int* in_sizes, int n_in,
                              void* d_out, int out_size, void* d_ws, size_t ws_size,
                              hipStream_t stream) {
    // Inputs (setup_inputs order): input (int32, unused), timestamp (f32),
    // W (f32, 8x1000), b (f32, 8).
    const float* timestamp = (const float*)d_in[1];
    const float* W         = (const float*)d_in[2];
    const float* bias      = (const float*)d_in[3];

    float* out = (float*)d_out;
    float* out_te = out;                                    // B*L*8 floats
    float* out_ts = out + (size_t)B_DIM * L_DIM * OD;       // B*L floats
    float* wt_g   = (float*)d_ws;                           // 32 KB table

    build_table<<<32, 256, 0, stream>>>(W, bias, wt_g);
    ste_kernel<<<NBLK, 256, 0, stream>>>(timestamp, wt_g, out_te, out_ts);
}